// Round 23
// baseline (280.709 us; speedup 1.0000x reference)
//
#include <hip/hip_runtime.h>

#define NV   100000
#define NE   50000
#define NNZ  3200000
#define KIN  256
#define KOUT 64

#define NB    256                  // hist/partition chunks (NNZ = 256*12500 exactly)
#define CHUNK (NNZ / NB)           // 12500
#define TS    6250                 // partsort tile size (CHUNK = 2*TS)
#define NBE   782                  // ceil(NE/64) edge buckets
#define NBV   1563                 // ceil(NV/64) vertex buckets
#define NBINS (NBE + NBV)          // 2345
#define LSCAN (NBINS * NB)         // 600320
#define NBLK_SCAN ((LSCAN + 1023) / 1024)   // 587 (<= 1024 for k_scan2)

// project slicing: 196 blocks x 512 rows, spread across 4 chain-stage kernels
#define PA 80
#define PB 50
#define PC 26
#define PD 40                      // PA+PB+PC+PD = 196

#define ECAP_E 6144                // E-bucket LDS capacity (mean 4096)
#define ECAP_V 4096                // V-bucket LDS capacity (mean 2048)

typedef short short8 __attribute__((ext_vector_type(8)));
typedef float f32x4  __attribute__((ext_vector_type(4)));

__device__ __forceinline__ unsigned short f2bf(float f) {
    union { float f; unsigned u; } c{f};
    const unsigned lsb = (c.u >> 16) & 1u;
    return (unsigned short)((c.u + 0x7FFFu + lsb) >> 16);
}
__device__ __forceinline__ float bf2f_lo(unsigned u) {
    union { unsigned u; float f; } c{u << 16};
    return c.f;
}
__device__ __forceinline__ float bf2f_hi(unsigned u) {
    union { unsigned u; float f; } c{u & 0xFFFF0000u};
    return c.f;
}
__device__ __forceinline__ short8 pack8(const float4 lo, const float4 hi) {
    short8 r;
    r[0] = (short)f2bf(lo.x); r[1] = (short)f2bf(lo.y);
    r[2] = (short)f2bf(lo.z); r[3] = (short)f2bf(lo.w);
    r[4] = (short)f2bf(hi.x); r[5] = (short)f2bf(hi.y);
    r[6] = (short)f2bf(hi.z); r[7] = (short)f2bf(hi.w);
    return r;
}

// ---------------------------------------------------------------------------
// One-off: Wb[o][k] = bf16(W[o][k])
// ---------------------------------------------------------------------------
__global__ __launch_bounds__(256) void k_wb(const float* __restrict__ W,
                                            unsigned short* __restrict__ Wb) {
    const int i = blockIdx.x * 256 + threadIdx.x;
    Wb[i] = f2bf(W[i]);
}

// ---------------------------------------------------------------------------
// Project body: 16-wave block pb handles rows [pb*512, pb*512+512).
// Zero-LDS MFMA GEMM (round-18 inner body; throughput-limited ~1.7 TB/s,
// so slices of the 196-block grid scale linearly -> can be co-scheduled
// with independent chain stages).
// ---------------------------------------------------------------------------
__device__ __forceinline__ void proj_body(int pb, int tid,
                                          const float* __restrict__ X,
                                          const unsigned short* __restrict__ Wb,
                                          unsigned short* __restrict__ Xpb) {
    const int lane = tid & 63;
    const int wv   = tid >> 6;              // 0..15
    const int l15  = lane & 15;
    const int l4   = lane >> 4;
    const int rbase = pb * 512 + wv * 32;

    const int r0 = min(rbase + l15,      NV - 1);
    const int r1 = min(rbase + 16 + l15, NV - 1);
    const float* xp0 = X + (size_t)r0 * KIN + l4 * 8;
    const float* xp1 = X + (size_t)r1 * KIN + l4 * 8;
    const unsigned short* wp = Wb + (size_t)l15 * KIN + l4 * 8;

    f32x4 acc[2][4];
#pragma unroll
    for (int t = 0; t < 2; ++t)
#pragma unroll
        for (int g = 0; g < 4; ++g)
            acc[t][g] = (f32x4){0.f, 0.f, 0.f, 0.f};

#pragma unroll
    for (int s = 0; s < 8; ++s) {
        const int k0 = s * 32;
        const float4 a0lo = *(const float4*)(xp0 + k0);
        const float4 a0hi = *(const float4*)(xp0 + k0 + 4);
        const float4 a1lo = *(const float4*)(xp1 + k0);
        const float4 a1hi = *(const float4*)(xp1 + k0 + 4);
        short8 b[4];
#pragma unroll
        for (int g = 0; g < 4; ++g)
            b[g] = *(const short8*)(wp + (size_t)g * 16 * KIN + k0);
        const short8 a0 = pack8(a0lo, a0hi);
        const short8 a1 = pack8(a1lo, a1hi);
#pragma unroll
        for (int g = 0; g < 4; ++g) {
            acc[0][g] = __builtin_amdgcn_mfma_f32_16x16x32_bf16(a0, b[g], acc[0][g], 0, 0, 0);
            acc[1][g] = __builtin_amdgcn_mfma_f32_16x16x32_bf16(a1, b[g], acc[1][g], 0, 0, 0);
        }
    }

#pragma unroll
    for (int t = 0; t < 2; ++t)
#pragma unroll
        for (int i = 0; i < 4; ++i) {
            const int r = rbase + t * 16 + l4 * 4 + i;
            if (r < NV) {
#pragma unroll
                for (int g = 0; g < 4; ++g)
                    Xpb[(size_t)r * KOUT + g * 16 + l15] = f2bf(acc[t][g][i]);
            }
        }
}

// ---------------------------------------------------------------------------
// K1: proj blocks [0,PA) || hist blocks [PA, PA+NB)
// ---------------------------------------------------------------------------
__global__ __launch_bounds__(1024) void k_st1(const float* __restrict__ X,
                                              const unsigned short* __restrict__ Wb,
                                              unsigned short* __restrict__ Xpb,
                                              const int* __restrict__ v_idx,
                                              const int* __restrict__ e_idx,
                                              int* __restrict__ mat) {
    const int tid = threadIdx.x;
    if (blockIdx.x < PA) {
        proj_body(blockIdx.x, tid, X, Wb, Xpb);
    } else {
        __shared__ int h[NBINS];
        const int bb = blockIdx.x - PA;
        for (int i = tid; i < NBINS; i += 1024) h[i] = 0;
        __syncthreads();
        const int base = bb * CHUNK;
        for (int i = tid; i < CHUNK; i += 1024) {
            atomicAdd(&h[e_idx[base + i] >> 6], 1);
            atomicAdd(&h[NBE + (v_idx[base + i] >> 6)], 1);
        }
        __syncthreads();
        for (int j = tid; j < NBINS; j += 1024) mat[j * NB + bb] = h[j];
    }
}

// ---------------------------------------------------------------------------
// K2: proj blocks [0,PB) (offset PA) || scan1 blocks [PB, PB+NBLK_SCAN)
// ---------------------------------------------------------------------------
__global__ __launch_bounds__(1024) void k_st2(const float* __restrict__ X,
                                              const unsigned short* __restrict__ Wb,
                                              unsigned short* __restrict__ Xpb,
                                              int* __restrict__ mat,
                                              int* __restrict__ bsum) {
    const int tid = threadIdx.x;
    if (blockIdx.x < PB) {
        proj_body(PA + blockIdx.x, tid, X, Wb, Xpb);
    } else {
        __shared__ int buf[1024];
        const int sb = blockIdx.x - PB;
        const int i = sb * 1024 + tid;
        const int v = (i < LSCAN) ? mat[i] : 0;
        buf[tid] = v;
        __syncthreads();
        for (int d = 1; d < 1024; d <<= 1) {
            int t = (tid >= d) ? buf[tid - d] : 0;
            __syncthreads();
            buf[tid] += t;
            __syncthreads();
        }
        if (i < LSCAN) mat[i] = buf[tid] - v;
        if (tid == 1023) bsum[sb] = buf[1023];
    }
}

// ---------------------------------------------------------------------------
// K3: proj blocks [0,PC) (offset PA+PB) || scan2 (single block)
// ---------------------------------------------------------------------------
__global__ __launch_bounds__(1024) void k_st3(const float* __restrict__ X,
                                              const unsigned short* __restrict__ Wb,
                                              unsigned short* __restrict__ Xpb,
                                              int* __restrict__ bsum) {
    const int tid = threadIdx.x;
    if (blockIdx.x < PC) {
        proj_body(PA + PB + blockIdx.x, tid, X, Wb, Xpb);
    } else {
        __shared__ int buf[1024];
        const int v = (tid < NBLK_SCAN) ? bsum[tid] : 0;
        buf[tid] = v;
        __syncthreads();
        for (int d = 1; d < 1024; d <<= 1) {
            int t = (tid >= d) ? buf[tid - d] : 0;
            __syncthreads();
            buf[tid] += t;
            __syncthreads();
        }
        if (tid < NBLK_SCAN) bsum[tid] = buf[tid] - v;
    }
}

// ---------------------------------------------------------------------------
// K4: proj blocks [0,PD) (offset PA+PB+PC) || scan3 blocks
// ---------------------------------------------------------------------------
__global__ __launch_bounds__(1024) void k_st4(const float* __restrict__ X,
                                              const unsigned short* __restrict__ Wb,
                                              unsigned short* __restrict__ Xpb,
                                              int* __restrict__ mat,
                                              const int* __restrict__ bsum) {
    const int tid = threadIdx.x;
    if (blockIdx.x < PD) {
        proj_body(PA + PB + PC + blockIdx.x, tid, X, Wb, Xpb);
    } else {
        const int sb = blockIdx.x - PD;
        const int i = sb * 1024 + tid;
        if (i < LSCAN) mat[i] += bsum[sb];
    }
}

// ---------------------------------------------------------------------------
// Combined E+V coalesced partition (round-22 form, unchanged): 2*NB blocks.
// ---------------------------------------------------------------------------
__global__ __launch_bounds__(1024) void k_partsort2(const int* __restrict__ v_idx,
                                                    const int* __restrict__ e_idx,
                                                    const int* __restrict__ mat,
                                                    unsigned* __restrict__ partE,
                                                    unsigned* __restrict__ partV) {
    __shared__ unsigned sbuf[TS];            // 25.0 KB
    __shared__ unsigned short binbuf[TS];    // 12.5 KB
    __shared__ int hist[NBV], pfx[NBV], cur[NBV], gdst[NBV];   // 25.0 KB (max side)
    const int side = (blockIdx.x >= NB) ? 1 : 0;
    const int b = blockIdx.x - side * NB;
    const int tid = threadIdx.x;
    const int nbin = side ? NBV : NBE;
    const int rowOff = side ? NBE : 0;
    const int sub    = side ? NNZ : 0;
    unsigned* __restrict__ part = side ? partV : partE;

    for (int j = tid; j < nbin; j += 1024)
        gdst[j] = mat[(rowOff + j) * NB + b] - sub;

    const int base = b * CHUNK;
    for (int tile = 0; tile < CHUNK / TS; ++tile) {
        __syncthreads();
        for (int j = tid; j < nbin; j += 1024) hist[j] = 0;
        __syncthreads();

        int sb[7]; unsigned svv[7];
#pragma unroll
        for (int s = 0; s < 7; ++s) {
            const int li = s * 1024 + tid;
            sb[s] = -1;
            if (li < TS) {
                const int i = base + tile * TS + li;
                const int v = v_idx[i], e = e_idx[i];
                int bin; unsigned val;
                if (side == 0) { bin = e >> 6; val = (unsigned)v | ((unsigned)(e & 63) << 17); }
                else           { bin = v >> 6; val = (unsigned)e | ((unsigned)(v & 63) << 17); }
                atomicAdd(&hist[bin], 1);
                sb[s] = bin; svv[s] = val;
            }
        }
        __syncthreads();

        if (tid < 64) {
            int carry = 0;
            for (int c = 0; c < nbin; c += 64) {
                const int j = c + tid;
                const int h = (j < nbin) ? hist[j] : 0;
                int x = h;
#pragma unroll
                for (int d = 1; d < 64; d <<= 1) {
                    const int y = __shfl_up(x, d, 64);
                    if (tid >= d) x += y;
                }
                if (j < nbin) pfx[j] = carry + x - h;
                carry += __shfl(x, 63, 64);
            }
        }
        __syncthreads();
        for (int j = tid; j < nbin; j += 1024) cur[j] = pfx[j];
        __syncthreads();

#pragma unroll
        for (int s = 0; s < 7; ++s) {
            if (sb[s] >= 0) {
                const int p = atomicAdd(&cur[sb[s]], 1);
                sbuf[p] = svv[s];
                binbuf[p] = (unsigned short)sb[s];
            }
        }
        __syncthreads();

        for (int li = tid; li < TS; li += 1024) {
            const int bin = binbuf[li];
            part[gdst[bin] + (li - pfx[bin])] = sbuf[li];
        }
        __syncthreads();
        for (int j = tid; j < nbin; j += 1024) gdst[j] += cur[j] - pfx[j];
    }
}

// ---------------------------------------------------------------------------
// Fused sort+gather, edge side (unchanged).
// ---------------------------------------------------------------------------
__global__ __launch_bounds__(1024) void k_sortgatherE(const unsigned* __restrict__ part,
                                                      const int* __restrict__ mat,
                                                      const unsigned short* __restrict__ Xpb,
                                                      const float* __restrict__ degE,
                                                      const float* __restrict__ Wdiag,
                                                      unsigned short* __restrict__ Xeb) {
    __shared__ unsigned sbuf[ECAP_E];       // 24 KB
    __shared__ int hist[64], cur[64], pfx[65];
    const int b = blockIdx.x, tid = threadIdx.x;
    const int base = mat[b * NB];
    const int end  = (b == NBE - 1) ? NNZ : mat[(b + 1) * NB];
    const int nb = end - base;

    if (tid < 64) hist[tid] = 0;
    __syncthreads();
    for (int i = tid; i < nb; i += 1024)
        atomicAdd(&hist[(part[base + i] >> 17) & 63], 1);
    __syncthreads();
    if (tid == 0) {
        int s = 0;
        for (int k = 0; k < 64; ++k) { pfx[k] = s; cur[k] = s; s += hist[k]; }
        pfx[64] = s;
    }
    __syncthreads();
    for (int i = tid; i < nb; i += 1024) {
        const unsigned u = part[base + i];
        const int p = atomicAdd(&cur[(u >> 17) & 63], 1);
        sbuf[p] = u & 0x1FFFFu;
    }
    __syncthreads();

    const int wv = tid >> 6, lane = tid & 63;
    const int q = lane >> 3, sl = lane & 7;
#pragma unroll
    for (int j = 0; j < 4; ++j) {
        const int le = wv * 4 + j;
        const int e_id = (b << 6) + le;
        const int s0 = pfx[le];
        const int n  = pfx[le + 1] - s0;
        float a0 = 0.f, a1 = 0.f, a2 = 0.f, a3 = 0.f,
              a4 = 0.f, a5 = 0.f, a6 = 0.f, a7 = 0.f;
        const int nf = n >> 3;
        int t = 0;
        for (; t + 4 <= nf; t += 4) {
            int idx[4]; uint4 u4[4];
#pragma unroll
            for (int z = 0; z < 4; ++z) idx[z] = (int)sbuf[s0 + 8 * (t + z) + q];
#pragma unroll
            for (int z = 0; z < 4; ++z)
                u4[z] = *(const uint4*)&Xpb[(size_t)idx[z] * KOUT + 8 * sl];
#pragma unroll
            for (int z = 0; z < 4; ++z) {
                a0 += bf2f_lo(u4[z].x); a1 += bf2f_hi(u4[z].x);
                a2 += bf2f_lo(u4[z].y); a3 += bf2f_hi(u4[z].y);
                a4 += bf2f_lo(u4[z].z); a5 += bf2f_hi(u4[z].z);
                a6 += bf2f_lo(u4[z].w); a7 += bf2f_hi(u4[z].w);
            }
        }
        for (; t < nf; ++t) {
            const int idx = (int)sbuf[s0 + 8 * t + q];
            const uint4 u = *(const uint4*)&Xpb[(size_t)idx * KOUT + 8 * sl];
            a0 += bf2f_lo(u.x); a1 += bf2f_hi(u.x);
            a2 += bf2f_lo(u.y); a3 += bf2f_hi(u.y);
            a4 += bf2f_lo(u.z); a5 += bf2f_hi(u.z);
            a6 += bf2f_lo(u.w); a7 += bf2f_hi(u.w);
        }
        if (n & 7) {
            const int src = nf * 8 + q;
            if (src < n) {
                const int idx = (int)sbuf[s0 + src];
                const uint4 u = *(const uint4*)&Xpb[(size_t)idx * KOUT + 8 * sl];
                a0 += bf2f_lo(u.x); a1 += bf2f_hi(u.x);
                a2 += bf2f_lo(u.y); a3 += bf2f_hi(u.y);
                a4 += bf2f_lo(u.z); a5 += bf2f_hi(u.z);
                a6 += bf2f_lo(u.w); a7 += bf2f_hi(u.w);
            }
        }
#pragma unroll
        for (int d = 8; d < 64; d <<= 1) {
            a0 += __shfl_xor(a0, d, 64); a1 += __shfl_xor(a1, d, 64);
            a2 += __shfl_xor(a2, d, 64); a3 += __shfl_xor(a3, d, 64);
            a4 += __shfl_xor(a4, d, 64); a5 += __shfl_xor(a5, d, 64);
            a6 += __shfl_xor(a6, d, 64); a7 += __shfl_xor(a7, d, 64);
        }
        if (q == 0 && e_id < NE) {
            const float s = degE[e_id] * Wdiag[e_id];
            uint4 pk;
            pk.x = (unsigned)f2bf(a0 * s) | ((unsigned)f2bf(a1 * s) << 16);
            pk.y = (unsigned)f2bf(a2 * s) | ((unsigned)f2bf(a3 * s) << 16);
            pk.z = (unsigned)f2bf(a4 * s) | ((unsigned)f2bf(a5 * s) << 16);
            pk.w = (unsigned)f2bf(a6 * s) | ((unsigned)f2bf(a7 * s) << 16);
            *(uint4*)&Xeb[(size_t)e_id * KOUT + 8 * sl] = pk;
        }
    }
}

// ---------------------------------------------------------------------------
// Fused sort+gather, vertex side (unchanged); f32 out.
// ---------------------------------------------------------------------------
__global__ __launch_bounds__(1024) void k_sortgatherV(const unsigned* __restrict__ part,
                                                      const int* __restrict__ mat,
                                                      const unsigned short* __restrict__ Xeb,
                                                      const float* __restrict__ degV,
                                                      float* __restrict__ out) {
    __shared__ unsigned sbuf[ECAP_V];       // 16 KB
    __shared__ int hist[64], cur[64], pfx[65];
    const int b = blockIdx.x, tid = threadIdx.x;
    const int base = mat[NBE * NB + b * NB] - NNZ;
    const int end  = (b == NBV - 1) ? NNZ : (mat[NBE * NB + (b + 1) * NB] - NNZ);
    const int nb = end - base;

    if (tid < 64) hist[tid] = 0;
    __syncthreads();
    for (int i = tid; i < nb; i += 1024)
        atomicAdd(&hist[(part[base + i] >> 17) & 63], 1);
    __syncthreads();
    if (tid == 0) {
        int s = 0;
        for (int k = 0; k < 64; ++k) { pfx[k] = s; cur[k] = s; s += hist[k]; }
        pfx[64] = s;
    }
    __syncthreads();
    for (int i = tid; i < nb; i += 1024) {
        const unsigned u = part[base + i];
        const int p = atomicAdd(&cur[(u >> 17) & 63], 1);
        sbuf[p] = u & 0x1FFFFu;
    }
    __syncthreads();

    const int wv = tid >> 6, lane = tid & 63;
    const int q = lane >> 3, sl = lane & 7;
#pragma unroll
    for (int j = 0; j < 4; ++j) {
        const int lv = wv * 4 + j;
        const int v_id = (b << 6) + lv;
        const int s0 = pfx[lv];
        const int n  = pfx[lv + 1] - s0;
        float a0 = 0.f, a1 = 0.f, a2 = 0.f, a3 = 0.f,
              a4 = 0.f, a5 = 0.f, a6 = 0.f, a7 = 0.f;
        const int nf = n >> 3;
        int t = 0;
        for (; t + 4 <= nf; t += 4) {
            int idx[4]; uint4 u4[4];
#pragma unroll
            for (int z = 0; z < 4; ++z) idx[z] = (int)sbuf[s0 + 8 * (t + z) + q];
#pragma unroll
            for (int z = 0; z < 4; ++z)
                u4[z] = *(const uint4*)&Xeb[(size_t)idx[z] * KOUT + 8 * sl];
#pragma unroll
            for (int z = 0; z < 4; ++z) {
                a0 += bf2f_lo(u4[z].x); a1 += bf2f_hi(u4[z].x);
                a2 += bf2f_lo(u4[z].y); a3 += bf2f_hi(u4[z].y);
                a4 += bf2f_lo(u4[z].z); a5 += bf2f_hi(u4[z].z);
                a6 += bf2f_lo(u4[z].w); a7 += bf2f_hi(u4[z].w);
            }
        }
        for (; t < nf; ++t) {
            const int idx = (int)sbuf[s0 + 8 * t + q];
            const uint4 u = *(const uint4*)&Xeb[(size_t)idx * KOUT + 8 * sl];
            a0 += bf2f_lo(u.x); a1 += bf2f_hi(u.x);
            a2 += bf2f_lo(u.y); a3 += bf2f_hi(u.y);
            a4 += bf2f_lo(u.z); a5 += bf2f_hi(u.z);
            a6 += bf2f_lo(u.w); a7 += bf2f_hi(u.w);
        }
        if (n & 7) {
            const int src = nf * 8 + q;
            if (src < n) {
                const int idx = (int)sbuf[s0 + src];
                const uint4 u = *(const uint4*)&Xeb[(size_t)idx * KOUT + 8 * sl];
                a0 += bf2f_lo(u.x); a1 += bf2f_hi(u.x);
                a2 += bf2f_lo(u.y); a3 += bf2f_hi(u.y);
                a4 += bf2f_lo(u.z); a5 += bf2f_hi(u.z);
                a6 += bf2f_lo(u.w); a7 += bf2f_hi(u.w);
            }
        }
#pragma unroll
        for (int d = 8; d < 64; d <<= 1) {
            a0 += __shfl_xor(a0, d, 64); a1 += __shfl_xor(a1, d, 64);
            a2 += __shfl_xor(a2, d, 64); a3 += __shfl_xor(a3, d, 64);
            a4 += __shfl_xor(a4, d, 64); a5 += __shfl_xor(a5, d, 64);
            a6 += __shfl_xor(a6, d, 64); a7 += __shfl_xor(a7, d, 64);
        }
        if (q == 0 && v_id < NV) {
            const float s = degV[v_id];
            *(float4*)&out[(size_t)v_id * KOUT + 8 * sl] =
                make_float4(a0 * s, a1 * s, a2 * s, a3 * s);
            *(float4*)&out[(size_t)v_id * KOUT + 8 * sl + 4] =
                make_float4(a4 * s, a5 * s, a6 * s, a7 * s);
        }
    }
}

extern "C" void kernel_launch(void* const* d_in, const int* in_sizes, int n_in,
                              void* d_out, int out_size, void* d_ws, size_t ws_size,
                              hipStream_t stream) {
    const float* X     = (const float*)d_in[0];
    const float* W     = (const float*)d_in[1];
    const float* degE  = (const float*)d_in[2];
    const float* degV  = (const float*)d_in[3];
    const float* Wdiag = (const float*)d_in[4];
    const int*   v_idx = (const int*)d_in[5];
    const int*   e_idx = (const int*)d_in[6];
    float* out = (float*)d_out;

    // Workspace (~48 MB)
    unsigned short* Xpb  = (unsigned short*)d_ws;             // NV*KOUT bf16
    unsigned short* Xeb  = Xpb + (size_t)NV * KOUT;           // NE*KOUT bf16
    unsigned*       partE = (unsigned*)(Xeb + (size_t)NE * KOUT); // NNZ u32
    unsigned*       partV = partE + NNZ;                      // NNZ u32
    int*            mat   = (int*)(partV + NNZ);              // LSCAN
    int*            bsum  = mat + LSCAN;                      // NBLK_SCAN
    unsigned short* Wb    = (unsigned short*)(bsum + ((NBLK_SCAN + 3) & ~3)); // 32 KB

    k_wb<<<(KIN * KOUT) / 256, 256, 0, stream>>>(W, Wb);

    // Pipelined front-end: each chain stage co-runs a project slice
    k_st1<<<PA + NB,        1024, 0, stream>>>(X, Wb, Xpb, v_idx, e_idx, mat);
    k_st2<<<PB + NBLK_SCAN, 1024, 0, stream>>>(X, Wb, Xpb, mat, bsum);
    k_st3<<<PC + 1,         1024, 0, stream>>>(X, Wb, Xpb, bsum);
    k_st4<<<PD + NBLK_SCAN, 1024, 0, stream>>>(X, Wb, Xpb, mat, bsum);

    // E and V coalesced partitions in ONE kernel (overlapped)
    k_partsort2<<<2 * NB, 1024, 0, stream>>>(v_idx, e_idx, mat, partE, partV);

    // Fused per-bucket sort + gather (eighth-wave: 8 entries/load round)
    k_sortgatherE<<<NBE, 1024, 0, stream>>>(partE, mat, Xpb, degE, Wdiag, Xeb);
    k_sortgatherV<<<NBV, 1024, 0, stream>>>(partV, mat, Xeb, degV, out);
}

// Round 24
// 214.591 us; speedup vs baseline: 1.3081x; 1.3081x over previous
//
#include <hip/hip_runtime.h>

#define NV   100000
#define NE   50000
#define NNZ  3200000
#define KIN  256
#define KOUT 64

#define NB    256                  // hist/partition chunks (NNZ = 256*12500 exactly)
#define CHUNK (NNZ / NB)           // 12500
#define TS    6250                 // partsort tile size (CHUNK = 2*TS)
#define NBE   782                  // ceil(NE/64) edge buckets
#define NBV   1563                 // ceil(NV/64) vertex buckets
#define NBINS (NBE + NBV)          // 2345
#define LSCAN (NBINS * NB)         // 600320
#define NBLK_SCAN ((LSCAN + 1023) / 1024)   // 587

#define PROJ_BLKS 196              // ceil(NV/512) project blocks in k_projhist

#define ECAP_E 6144                // E-bucket LDS capacity (mean 4096)
#define ECAP_V 4096                // V-bucket LDS capacity (mean 2048)

typedef short short8 __attribute__((ext_vector_type(8)));
typedef float f32x4  __attribute__((ext_vector_type(4)));

__device__ __forceinline__ unsigned short f2bf(float f) {
    union { float f; unsigned u; } c{f};
    const unsigned lsb = (c.u >> 16) & 1u;
    return (unsigned short)((c.u + 0x7FFFu + lsb) >> 16);
}
__device__ __forceinline__ float bf2f_lo(unsigned u) {
    union { unsigned u; float f; } c{u << 16};
    return c.f;
}
__device__ __forceinline__ float bf2f_hi(unsigned u) {
    union { unsigned u; float f; } c{u & 0xFFFF0000u};
    return c.f;
}
__device__ __forceinline__ short8 pack8(const float4 lo, const float4 hi) {
    short8 r;
    r[0] = (short)f2bf(lo.x); r[1] = (short)f2bf(lo.y);
    r[2] = (short)f2bf(lo.z); r[3] = (short)f2bf(lo.w);
    r[4] = (short)f2bf(hi.x); r[5] = (short)f2bf(hi.y);
    r[6] = (short)f2bf(hi.z); r[7] = (short)f2bf(hi.w);
    return r;
}

// ---------------------------------------------------------------------------
// Fused project + histogram (round-22 structure). Project packs BOTH A and B
// fragments from f32 in-register (no Wb precompute kernel; W is L2-resident).
// ---------------------------------------------------------------------------
__global__ __launch_bounds__(1024) void k_projhist(const float* __restrict__ X,
                                                   const float* __restrict__ W,
                                                   unsigned short* __restrict__ Xpb,
                                                   const int* __restrict__ v_idx,
                                                   const int* __restrict__ e_idx,
                                                   int* __restrict__ mat) {
    __shared__ int h[NBINS];   // used only by hist blocks (9.4 KB)
    if (blockIdx.x < PROJ_BLKS) {
        const int tid  = threadIdx.x;
        const int lane = tid & 63;
        const int wv   = tid >> 6;              // 0..15
        const int l15  = lane & 15;
        const int l4   = lane >> 4;
        const int rbase = blockIdx.x * 512 + wv * 32;

        const int r0 = min(rbase + l15,      NV - 1);
        const int r1 = min(rbase + 16 + l15, NV - 1);
        const float* xp0 = X + (size_t)r0 * KIN + l4 * 8;
        const float* xp1 = X + (size_t)r1 * KIN + l4 * 8;
        const float* wfp = W + (size_t)l15 * KIN + l4 * 8;

        f32x4 acc[2][4];
#pragma unroll
        for (int t = 0; t < 2; ++t)
#pragma unroll
            for (int g = 0; g < 4; ++g)
                acc[t][g] = (f32x4){0.f, 0.f, 0.f, 0.f};

#pragma unroll
        for (int s = 0; s < 8; ++s) {
            const int k0 = s * 32;
            const float4 a0lo = *(const float4*)(xp0 + k0);
            const float4 a0hi = *(const float4*)(xp0 + k0 + 4);
            const float4 a1lo = *(const float4*)(xp1 + k0);
            const float4 a1hi = *(const float4*)(xp1 + k0 + 4);
            short8 b[4];
#pragma unroll
            for (int g = 0; g < 4; ++g) {
                const float* wg = wfp + (size_t)g * 16 * KIN + k0;
                b[g] = pack8(*(const float4*)wg, *(const float4*)(wg + 4));
            }
            const short8 a0 = pack8(a0lo, a0hi);
            const short8 a1 = pack8(a1lo, a1hi);
#pragma unroll
            for (int g = 0; g < 4; ++g) {
                acc[0][g] = __builtin_amdgcn_mfma_f32_16x16x32_bf16(a0, b[g], acc[0][g], 0, 0, 0);
                acc[1][g] = __builtin_amdgcn_mfma_f32_16x16x32_bf16(a1, b[g], acc[1][g], 0, 0, 0);
            }
        }

#pragma unroll
        for (int t = 0; t < 2; ++t)
#pragma unroll
            for (int i = 0; i < 4; ++i) {
                const int r = rbase + t * 16 + l4 * 4 + i;
                if (r < NV) {
#pragma unroll
                    for (int g = 0; g < 4; ++g)
                        Xpb[(size_t)r * KOUT + g * 16 + l15] = f2bf(acc[t][g][i]);
                }
            }
    } else {
        const int bb = blockIdx.x - PROJ_BLKS;  // 0..NB-1
        const int tid = threadIdx.x;
        for (int i = tid; i < NBINS; i += 1024) h[i] = 0;
        __syncthreads();
        const int base = bb * CHUNK;
        for (int i = tid; i < CHUNK; i += 1024) {
            atomicAdd(&h[e_idx[base + i] >> 6], 1);
            atomicAdd(&h[NBE + (v_idx[base + i] >> 6)], 1);
        }
        __syncthreads();
        for (int j = tid; j < NBINS; j += 1024) mat[j * NB + bb] = h[j];
    }
}

// ---------------------------------------------------------------------------
// scan1: per-block local exclusive scan + block sums (raw, NOT scanned)
// ---------------------------------------------------------------------------
__global__ __launch_bounds__(1024) void k_scan1(int* __restrict__ mat,
                                                int* __restrict__ bsum) {
    __shared__ int buf[1024];
    const int tid = threadIdx.x;
    const int i = blockIdx.x * 1024 + tid;
    const int v = (i < LSCAN) ? mat[i] : 0;
    buf[tid] = v;
    __syncthreads();
    for (int d = 1; d < 1024; d <<= 1) {
        int t = (tid >= d) ? buf[tid - d] : 0;
        __syncthreads();
        buf[tid] += t;
        __syncthreads();
    }
    if (i < LSCAN) mat[i] = buf[tid] - v;
    if (tid == 1023) bsum[blockIdx.x] = buf[1023];
}

// ---------------------------------------------------------------------------
// scan23 (merged): each block reduces bsum[k < blockIdx] -> its global offset,
// then adds it to its 1024 mat elements. bsum is 2.3 KB, L2-hot.
// ---------------------------------------------------------------------------
__global__ __launch_bounds__(1024) void k_scan23(int* __restrict__ mat,
                                                 const int* __restrict__ bsum) {
    __shared__ int red[1024];
    const int tid = threadIdx.x;
    const int b = blockIdx.x;
    int p = 0;
    for (int k = tid; k < b; k += 1024) p += bsum[k];   // k < b <= 587
    red[tid] = p;
    __syncthreads();
    for (int d = 512; d > 0; d >>= 1) {
        if (tid < d) red[tid] += red[tid + d];
        __syncthreads();
    }
    const int off = red[0];
    const int i = b * 1024 + tid;
    if (i < LSCAN) mat[i] += off;
}

// ---------------------------------------------------------------------------
// Combined E+V coalesced partition (round-22 form): 2*NB blocks.
// ---------------------------------------------------------------------------
__global__ __launch_bounds__(1024) void k_partsort2(const int* __restrict__ v_idx,
                                                    const int* __restrict__ e_idx,
                                                    const int* __restrict__ mat,
                                                    unsigned* __restrict__ partE,
                                                    unsigned* __restrict__ partV) {
    __shared__ unsigned sbuf[TS];            // 25.0 KB
    __shared__ unsigned short binbuf[TS];    // 12.5 KB
    __shared__ int hist[NBV], pfx[NBV], cur[NBV], gdst[NBV];   // 25.0 KB (max side)
    const int side = (blockIdx.x >= NB) ? 1 : 0;
    const int b = blockIdx.x - side * NB;
    const int tid = threadIdx.x;
    const int nbin = side ? NBV : NBE;
    const int rowOff = side ? NBE : 0;
    const int sub    = side ? NNZ : 0;
    unsigned* __restrict__ part = side ? partV : partE;

    for (int j = tid; j < nbin; j += 1024)
        gdst[j] = mat[(rowOff + j) * NB + b] - sub;

    const int base = b * CHUNK;
    for (int tile = 0; tile < CHUNK / TS; ++tile) {
        __syncthreads();
        for (int j = tid; j < nbin; j += 1024) hist[j] = 0;
        __syncthreads();

        int sb[7]; unsigned svv[7];
#pragma unroll
        for (int s = 0; s < 7; ++s) {
            const int li = s * 1024 + tid;
            sb[s] = -1;
            if (li < TS) {
                const int i = base + tile * TS + li;
                const int v = v_idx[i], e = e_idx[i];
                int bin; unsigned val;
                if (side == 0) { bin = e >> 6; val = (unsigned)v | ((unsigned)(e & 63) << 17); }
                else           { bin = v >> 6; val = (unsigned)e | ((unsigned)(v & 63) << 17); }
                atomicAdd(&hist[bin], 1);
                sb[s] = bin; svv[s] = val;
            }
        }
        __syncthreads();

        if (tid < 64) {
            int carry = 0;
            for (int c = 0; c < nbin; c += 64) {
                const int j = c + tid;
                const int h = (j < nbin) ? hist[j] : 0;
                int x = h;
#pragma unroll
                for (int d = 1; d < 64; d <<= 1) {
                    const int y = __shfl_up(x, d, 64);
                    if (tid >= d) x += y;
                }
                if (j < nbin) pfx[j] = carry + x - h;
                carry += __shfl(x, 63, 64);
            }
        }
        __syncthreads();
        for (int j = tid; j < nbin; j += 1024) cur[j] = pfx[j];
        __syncthreads();

#pragma unroll
        for (int s = 0; s < 7; ++s) {
            if (sb[s] >= 0) {
                const int p = atomicAdd(&cur[sb[s]], 1);
                sbuf[p] = svv[s];
                binbuf[p] = (unsigned short)sb[s];
            }
        }
        __syncthreads();

        for (int li = tid; li < TS; li += 1024) {
            const int bin = binbuf[li];
            part[gdst[bin] + (li - pfx[bin])] = sbuf[li];
        }
        __syncthreads();
        for (int j = tid; j < nbin; j += 1024) gdst[j] += cur[j] - pfx[j];
    }
}

// ---------------------------------------------------------------------------
// Fused sort+gather, edge side: one block per 64-edge bucket.
// ---------------------------------------------------------------------------
__global__ __launch_bounds__(1024) void k_sortgatherE(const unsigned* __restrict__ part,
                                                      const int* __restrict__ mat,
                                                      const unsigned short* __restrict__ Xpb,
                                                      const float* __restrict__ degE,
                                                      const float* __restrict__ Wdiag,
                                                      unsigned short* __restrict__ Xeb) {
    __shared__ unsigned sbuf[ECAP_E];       // 24 KB
    __shared__ int hist[64], cur[64], pfx[65];
    const int b = blockIdx.x, tid = threadIdx.x;
    const int base = mat[b * NB];
    const int end  = (b == NBE - 1) ? NNZ : mat[(b + 1) * NB];
    const int nb = end - base;

    if (tid < 64) hist[tid] = 0;
    __syncthreads();
    for (int i = tid; i < nb; i += 1024)
        atomicAdd(&hist[(part[base + i] >> 17) & 63], 1);
    __syncthreads();
    if (tid == 0) {
        int s = 0;
        for (int k = 0; k < 64; ++k) { pfx[k] = s; cur[k] = s; s += hist[k]; }
        pfx[64] = s;
    }
    __syncthreads();
    for (int i = tid; i < nb; i += 1024) {
        const unsigned u = part[base + i];
        const int p = atomicAdd(&cur[(u >> 17) & 63], 1);
        sbuf[p] = u & 0x1FFFFu;
    }
    __syncthreads();

    const int wv = tid >> 6, lane = tid & 63;
    const int q = lane >> 3, sl = lane & 7;
#pragma unroll
    for (int j = 0; j < 4; ++j) {
        const int le = wv * 4 + j;
        const int e_id = (b << 6) + le;
        const int s0 = pfx[le];
        const int n  = pfx[le + 1] - s0;
        float a0 = 0.f, a1 = 0.f, a2 = 0.f, a3 = 0.f,
              a4 = 0.f, a5 = 0.f, a6 = 0.f, a7 = 0.f;
        const int nf = n >> 3;
        int t = 0;
        for (; t + 4 <= nf; t += 4) {
            int idx[4]; uint4 u4[4];
#pragma unroll
            for (int z = 0; z < 4; ++z) idx[z] = (int)sbuf[s0 + 8 * (t + z) + q];
#pragma unroll
            for (int z = 0; z < 4; ++z)
                u4[z] = *(const uint4*)&Xpb[(size_t)idx[z] * KOUT + 8 * sl];
#pragma unroll
            for (int z = 0; z < 4; ++z) {
                a0 += bf2f_lo(u4[z].x); a1 += bf2f_hi(u4[z].x);
                a2 += bf2f_lo(u4[z].y); a3 += bf2f_hi(u4[z].y);
                a4 += bf2f_lo(u4[z].z); a5 += bf2f_hi(u4[z].z);
                a6 += bf2f_lo(u4[z].w); a7 += bf2f_hi(u4[z].w);
            }
        }
        for (; t < nf; ++t) {
            const int idx = (int)sbuf[s0 + 8 * t + q];
            const uint4 u = *(const uint4*)&Xpb[(size_t)idx * KOUT + 8 * sl];
            a0 += bf2f_lo(u.x); a1 += bf2f_hi(u.x);
            a2 += bf2f_lo(u.y); a3 += bf2f_hi(u.y);
            a4 += bf2f_lo(u.z); a5 += bf2f_hi(u.z);
            a6 += bf2f_lo(u.w); a7 += bf2f_hi(u.w);
        }
        if (n & 7) {
            const int src = nf * 8 + q;
            if (src < n) {
                const int idx = (int)sbuf[s0 + src];
                const uint4 u = *(const uint4*)&Xpb[(size_t)idx * KOUT + 8 * sl];
                a0 += bf2f_lo(u.x); a1 += bf2f_hi(u.x);
                a2 += bf2f_lo(u.y); a3 += bf2f_hi(u.y);
                a4 += bf2f_lo(u.z); a5 += bf2f_hi(u.z);
                a6 += bf2f_lo(u.w); a7 += bf2f_hi(u.w);
            }
        }
#pragma unroll
        for (int d = 8; d < 64; d <<= 1) {
            a0 += __shfl_xor(a0, d, 64); a1 += __shfl_xor(a1, d, 64);
            a2 += __shfl_xor(a2, d, 64); a3 += __shfl_xor(a3, d, 64);
            a4 += __shfl_xor(a4, d, 64); a5 += __shfl_xor(a5, d, 64);
            a6 += __shfl_xor(a6, d, 64); a7 += __shfl_xor(a7, d, 64);
        }
        if (q == 0 && e_id < NE) {
            const float s = degE[e_id] * Wdiag[e_id];
            uint4 pk;
            pk.x = (unsigned)f2bf(a0 * s) | ((unsigned)f2bf(a1 * s) << 16);
            pk.y = (unsigned)f2bf(a2 * s) | ((unsigned)f2bf(a3 * s) << 16);
            pk.z = (unsigned)f2bf(a4 * s) | ((unsigned)f2bf(a5 * s) << 16);
            pk.w = (unsigned)f2bf(a6 * s) | ((unsigned)f2bf(a7 * s) << 16);
            *(uint4*)&Xeb[(size_t)e_id * KOUT + 8 * sl] = pk;
        }
    }
}

// ---------------------------------------------------------------------------
// Fused sort+gather, vertex side: one block per 64-vertex bucket; f32 out.
// ---------------------------------------------------------------------------
__global__ __launch_bounds__(1024) void k_sortgatherV(const unsigned* __restrict__ part,
                                                      const int* __restrict__ mat,
                                                      const unsigned short* __restrict__ Xeb,
                                                      const float* __restrict__ degV,
                                                      float* __restrict__ out) {
    __shared__ unsigned sbuf[ECAP_V];       // 16 KB
    __shared__ int hist[64], cur[64], pfx[65];
    const int b = blockIdx.x, tid = threadIdx.x;
    const int base = mat[NBE * NB + b * NB] - NNZ;
    const int end  = (b == NBV - 1) ? NNZ : (mat[NBE * NB + (b + 1) * NB] - NNZ);
    const int nb = end - base;

    if (tid < 64) hist[tid] = 0;
    __syncthreads();
    for (int i = tid; i < nb; i += 1024)
        atomicAdd(&hist[(part[base + i] >> 17) & 63], 1);
    __syncthreads();
    if (tid == 0) {
        int s = 0;
        for (int k = 0; k < 64; ++k) { pfx[k] = s; cur[k] = s; s += hist[k]; }
        pfx[64] = s;
    }
    __syncthreads();
    for (int i = tid; i < nb; i += 1024) {
        const unsigned u = part[base + i];
        const int p = atomicAdd(&cur[(u >> 17) & 63], 1);
        sbuf[p] = u & 0x1FFFFu;
    }
    __syncthreads();

    const int wv = tid >> 6, lane = tid & 63;
    const int q = lane >> 3, sl = lane & 7;
#pragma unroll
    for (int j = 0; j < 4; ++j) {
        const int lv = wv * 4 + j;
        const int v_id = (b << 6) + lv;
        const int s0 = pfx[lv];
        const int n  = pfx[lv + 1] - s0;
        float a0 = 0.f, a1 = 0.f, a2 = 0.f, a3 = 0.f,
              a4 = 0.f, a5 = 0.f, a6 = 0.f, a7 = 0.f;
        const int nf = n >> 3;
        int t = 0;
        for (; t + 4 <= nf; t += 4) {
            int idx[4]; uint4 u4[4];
#pragma unroll
            for (int z = 0; z < 4; ++z) idx[z] = (int)sbuf[s0 + 8 * (t + z) + q];
#pragma unroll
            for (int z = 0; z < 4; ++z)
                u4[z] = *(const uint4*)&Xeb[(size_t)idx[z] * KOUT + 8 * sl];
#pragma unroll
            for (int z = 0; z < 4; ++z) {
                a0 += bf2f_lo(u4[z].x); a1 += bf2f_hi(u4[z].x);
                a2 += bf2f_lo(u4[z].y); a3 += bf2f_hi(u4[z].y);
                a4 += bf2f_lo(u4[z].z); a5 += bf2f_hi(u4[z].z);
                a6 += bf2f_lo(u4[z].w); a7 += bf2f_hi(u4[z].w);
            }
        }
        for (; t < nf; ++t) {
            const int idx = (int)sbuf[s0 + 8 * t + q];
            const uint4 u = *(const uint4*)&Xeb[(size_t)idx * KOUT + 8 * sl];
            a0 += bf2f_lo(u.x); a1 += bf2f_hi(u.x);
            a2 += bf2f_lo(u.y); a3 += bf2f_hi(u.y);
            a4 += bf2f_lo(u.z); a5 += bf2f_hi(u.z);
            a6 += bf2f_lo(u.w); a7 += bf2f_hi(u.w);
        }
        if (n & 7) {
            const int src = nf * 8 + q;
            if (src < n) {
                const int idx = (int)sbuf[s0 + src];
                const uint4 u = *(const uint4*)&Xeb[(size_t)idx * KOUT + 8 * sl];
                a0 += bf2f_lo(u.x); a1 += bf2f_hi(u.x);
                a2 += bf2f_lo(u.y); a3 += bf2f_hi(u.y);
                a4 += bf2f_lo(u.z); a5 += bf2f_hi(u.z);
                a6 += bf2f_lo(u.w); a7 += bf2f_hi(u.w);
            }
        }
#pragma unroll
        for (int d = 8; d < 64; d <<= 1) {
            a0 += __shfl_xor(a0, d, 64); a1 += __shfl_xor(a1, d, 64);
            a2 += __shfl_xor(a2, d, 64); a3 += __shfl_xor(a3, d, 64);
            a4 += __shfl_xor(a4, d, 64); a5 += __shfl_xor(a5, d, 64);
            a6 += __shfl_xor(a6, d, 64); a7 += __shfl_xor(a7, d, 64);
        }
        if (q == 0 && v_id < NV) {
            const float s = degV[v_id];
            *(float4*)&out[(size_t)v_id * KOUT + 8 * sl] =
                make_float4(a0 * s, a1 * s, a2 * s, a3 * s);
            *(float4*)&out[(size_t)v_id * KOUT + 8 * sl + 4] =
                make_float4(a4 * s, a5 * s, a6 * s, a7 * s);
        }
    }
}

extern "C" void kernel_launch(void* const* d_in, const int* in_sizes, int n_in,
                              void* d_out, int out_size, void* d_ws, size_t ws_size,
                              hipStream_t stream) {
    const float* X     = (const float*)d_in[0];
    const float* W     = (const float*)d_in[1];
    const float* degE  = (const float*)d_in[2];
    const float* degV  = (const float*)d_in[3];
    const float* Wdiag = (const float*)d_in[4];
    const int*   v_idx = (const int*)d_in[5];
    const int*   e_idx = (const int*)d_in[6];
    float* out = (float*)d_out;

    // Workspace (~48 MB)
    unsigned short* Xpb  = (unsigned short*)d_ws;             // NV*KOUT bf16
    unsigned short* Xeb  = Xpb + (size_t)NV * KOUT;           // NE*KOUT bf16
    unsigned*       partE = (unsigned*)(Xeb + (size_t)NE * KOUT); // NNZ u32
    unsigned*       partV = partE + NNZ;                      // NNZ u32
    int*            mat   = (int*)(partV + NNZ);              // LSCAN
    int*            bsum  = mat + LSCAN;                      // NBLK_SCAN

    // Project (blocks 0..195, W packed in-register) || histogram (196..451)
    k_projhist<<<PROJ_BLKS + NB, 1024, 0, stream>>>(X, W, Xpb, v_idx, e_idx, mat);

    k_scan1<<<NBLK_SCAN, 1024, 0, stream>>>(mat, bsum);
    k_scan23<<<NBLK_SCAN, 1024, 0, stream>>>(mat, bsum);

    // E and V coalesced partitions in ONE kernel (overlapped)
    k_partsort2<<<2 * NB, 1024, 0, stream>>>(v_idx, e_idx, mat, partE, partV);

    // Fused per-bucket sort + gather (eighth-wave: 8 entries/load round)
    k_sortgatherE<<<NBE, 1024, 0, stream>>>(partE, mat, Xpb, degE, Wdiag, Xeb);
    k_sortgatherV<<<NBV, 1024, 0, stream>>>(partV, mat, Xeb, degV, out);
}

// Round 25
// 207.486 us; speedup vs baseline: 1.3529x; 1.0342x over previous
//
#include <hip/hip_runtime.h>

#define NV   100000
#define NE   50000
#define NNZ  3200000
#define KIN  256
#define KOUT 64

#define NB    256                  // hist/partition chunks (NNZ = 256*12500 exactly)
#define CHUNK (NNZ / NB)           // 12500
#define TS    6250                 // partsort tile size (CHUNK = 2*TS)
#define NBE   782                  // ceil(NE/64) edge buckets
#define NBV   1563                 // ceil(NV/64) vertex buckets
#define NBINS (NBE + NBV)          // 2345
#define LSCAN (NBINS * NB)         // 600320
#define NBLK_SCAN ((LSCAN + 1023) / 1024)   // 587

#define PROJ_BLKS 196              // ceil(NV/512) project blocks in k_projhist

#define ECAP_E 6144                // E-bucket LDS capacity (mean 4096)
#define ECAP_V 4096                // V-bucket LDS capacity (mean 2048)

typedef short short8 __attribute__((ext_vector_type(8)));
typedef float f32x4  __attribute__((ext_vector_type(4)));

__device__ __forceinline__ unsigned short f2bf(float f) {
    union { float f; unsigned u; } c{f};
    const unsigned lsb = (c.u >> 16) & 1u;
    return (unsigned short)((c.u + 0x7FFFu + lsb) >> 16);
}
__device__ __forceinline__ float bf2f_lo(unsigned u) {
    union { unsigned u; float f; } c{u << 16};
    return c.f;
}
__device__ __forceinline__ float bf2f_hi(unsigned u) {
    union { unsigned u; float f; } c{u & 0xFFFF0000u};
    return c.f;
}
__device__ __forceinline__ short8 pack8(const float4 lo, const float4 hi) {
    short8 r;
    r[0] = (short)f2bf(lo.x); r[1] = (short)f2bf(lo.y);
    r[2] = (short)f2bf(lo.z); r[3] = (short)f2bf(lo.w);
    r[4] = (short)f2bf(hi.x); r[5] = (short)f2bf(hi.y);
    r[6] = (short)f2bf(hi.z); r[7] = (short)f2bf(hi.w);
    return r;
}

// ---------------------------------------------------------------------------
// One-off: Wb[o][k] = bf16(W[o][k])  (64 KB table; amortized over 196 blocks
// x 8 k-steps — measured cheaper than in-register f32 W packing, round 24)
// ---------------------------------------------------------------------------
__global__ __launch_bounds__(256) void k_wb(const float* __restrict__ W,
                                            unsigned short* __restrict__ Wb) {
    const int i = blockIdx.x * 256 + threadIdx.x;
    Wb[i] = f2bf(W[i]);
}

// ---------------------------------------------------------------------------
// Fused project + histogram (round-22 form, measured 71 us).
// Blocks [0,PROJ_BLKS): zero-LDS bf16 MFMA GEMM (16 waves x 32 rows).
// Blocks [PROJ_BLKS, +NB): 1024-thread bucket histogram (hides under GEMM).
// ---------------------------------------------------------------------------
__global__ __launch_bounds__(1024) void k_projhist(const float* __restrict__ X,
                                                   const unsigned short* __restrict__ Wb,
                                                   unsigned short* __restrict__ Xpb,
                                                   const int* __restrict__ v_idx,
                                                   const int* __restrict__ e_idx,
                                                   int* __restrict__ mat) {
    __shared__ int h[NBINS];   // used only by hist blocks (9.4 KB)
    if (blockIdx.x < PROJ_BLKS) {
        const int tid  = threadIdx.x;
        const int lane = tid & 63;
        const int wv   = tid >> 6;              // 0..15
        const int l15  = lane & 15;
        const int l4   = lane >> 4;
        const int rbase = blockIdx.x * 512 + wv * 32;

        const int r0 = min(rbase + l15,      NV - 1);
        const int r1 = min(rbase + 16 + l15, NV - 1);
        const float* xp0 = X + (size_t)r0 * KIN + l4 * 8;
        const float* xp1 = X + (size_t)r1 * KIN + l4 * 8;
        const unsigned short* wp = Wb + (size_t)l15 * KIN + l4 * 8;

        f32x4 acc[2][4];
#pragma unroll
        for (int t = 0; t < 2; ++t)
#pragma unroll
            for (int g = 0; g < 4; ++g)
                acc[t][g] = (f32x4){0.f, 0.f, 0.f, 0.f};

#pragma unroll
        for (int s = 0; s < 8; ++s) {
            const int k0 = s * 32;
            const float4 a0lo = *(const float4*)(xp0 + k0);
            const float4 a0hi = *(const float4*)(xp0 + k0 + 4);
            const float4 a1lo = *(const float4*)(xp1 + k0);
            const float4 a1hi = *(const float4*)(xp1 + k0 + 4);
            short8 b[4];
#pragma unroll
            for (int g = 0; g < 4; ++g)
                b[g] = *(const short8*)(wp + (size_t)g * 16 * KIN + k0);
            const short8 a0 = pack8(a0lo, a0hi);
            const short8 a1 = pack8(a1lo, a1hi);
#pragma unroll
            for (int g = 0; g < 4; ++g) {
                acc[0][g] = __builtin_amdgcn_mfma_f32_16x16x32_bf16(a0, b[g], acc[0][g], 0, 0, 0);
                acc[1][g] = __builtin_amdgcn_mfma_f32_16x16x32_bf16(a1, b[g], acc[1][g], 0, 0, 0);
            }
        }

#pragma unroll
        for (int t = 0; t < 2; ++t)
#pragma unroll
            for (int i = 0; i < 4; ++i) {
                const int r = rbase + t * 16 + l4 * 4 + i;
                if (r < NV) {
#pragma unroll
                    for (int g = 0; g < 4; ++g)
                        Xpb[(size_t)r * KOUT + g * 16 + l15] = f2bf(acc[t][g][i]);
                }
            }
    } else {
        const int bb = blockIdx.x - PROJ_BLKS;  // 0..NB-1
        const int tid = threadIdx.x;
        for (int i = tid; i < NBINS; i += 1024) h[i] = 0;
        __syncthreads();
        const int base = bb * CHUNK;
        for (int i = tid; i < CHUNK; i += 1024) {
            atomicAdd(&h[e_idx[base + i] >> 6], 1);
            atomicAdd(&h[NBE + (v_idx[base + i] >> 6)], 1);
        }
        __syncthreads();
        for (int j = tid; j < NBINS; j += 1024) mat[j * NB + bb] = h[j];
    }
}

// ---------------------------------------------------------------------------
// scan1: per-block local exclusive scan + raw block sums
// ---------------------------------------------------------------------------
__global__ __launch_bounds__(1024) void k_scan1(int* __restrict__ mat,
                                                int* __restrict__ bsum) {
    __shared__ int buf[1024];
    const int tid = threadIdx.x;
    const int i = blockIdx.x * 1024 + tid;
    const int v = (i < LSCAN) ? mat[i] : 0;
    buf[tid] = v;
    __syncthreads();
    for (int d = 1; d < 1024; d <<= 1) {
        int t = (tid >= d) ? buf[tid - d] : 0;
        __syncthreads();
        buf[tid] += t;
        __syncthreads();
    }
    if (i < LSCAN) mat[i] = buf[tid] - v;
    if (tid == 1023) bsum[blockIdx.x] = buf[1023];
}

// ---------------------------------------------------------------------------
// scan23 (merged, round-24 form): each block reduces bsum[k < blockIdx] to
// get its global offset, then adds to its 1024 mat elements (bsum L2-hot).
// ---------------------------------------------------------------------------
__global__ __launch_bounds__(1024) void k_scan23(int* __restrict__ mat,
                                                 const int* __restrict__ bsum) {
    __shared__ int red[1024];
    const int tid = threadIdx.x;
    const int b = blockIdx.x;
    int p = 0;
    for (int k = tid; k < b; k += 1024) p += bsum[k];   // k < b <= 587
    red[tid] = p;
    __syncthreads();
    for (int d = 512; d > 0; d >>= 1) {
        if (tid < d) red[tid] += red[tid + d];
        __syncthreads();
    }
    const int off = red[0];
    const int i = b * 1024 + tid;
    if (i < LSCAN) mat[i] += off;
}

// ---------------------------------------------------------------------------
// Combined E+V coalesced partition (round-22 form): 2*NB blocks.
// ---------------------------------------------------------------------------
__global__ __launch_bounds__(1024) void k_partsort2(const int* __restrict__ v_idx,
                                                    const int* __restrict__ e_idx,
                                                    const int* __restrict__ mat,
                                                    unsigned* __restrict__ partE,
                                                    unsigned* __restrict__ partV) {
    __shared__ unsigned sbuf[TS];            // 25.0 KB
    __shared__ unsigned short binbuf[TS];    // 12.5 KB
    __shared__ int hist[NBV], pfx[NBV], cur[NBV], gdst[NBV];   // 25.0 KB (max side)
    const int side = (blockIdx.x >= NB) ? 1 : 0;
    const int b = blockIdx.x - side * NB;
    const int tid = threadIdx.x;
    const int nbin = side ? NBV : NBE;
    const int rowOff = side ? NBE : 0;
    const int sub    = side ? NNZ : 0;
    unsigned* __restrict__ part = side ? partV : partE;

    for (int j = tid; j < nbin; j += 1024)
        gdst[j] = mat[(rowOff + j) * NB + b] - sub;

    const int base = b * CHUNK;
    for (int tile = 0; tile < CHUNK / TS; ++tile) {
        __syncthreads();
        for (int j = tid; j < nbin; j += 1024) hist[j] = 0;
        __syncthreads();

        int sb[7]; unsigned svv[7];
#pragma unroll
        for (int s = 0; s < 7; ++s) {
            const int li = s * 1024 + tid;
            sb[s] = -1;
            if (li < TS) {
                const int i = base + tile * TS + li;
                const int v = v_idx[i], e = e_idx[i];
                int bin; unsigned val;
                if (side == 0) { bin = e >> 6; val = (unsigned)v | ((unsigned)(e & 63) << 17); }
                else           { bin = v >> 6; val = (unsigned)e | ((unsigned)(v & 63) << 17); }
                atomicAdd(&hist[bin], 1);
                sb[s] = bin; svv[s] = val;
            }
        }
        __syncthreads();

        if (tid < 64) {
            int carry = 0;
            for (int c = 0; c < nbin; c += 64) {
                const int j = c + tid;
                const int h = (j < nbin) ? hist[j] : 0;
                int x = h;
#pragma unroll
                for (int d = 1; d < 64; d <<= 1) {
                    const int y = __shfl_up(x, d, 64);
                    if (tid >= d) x += y;
                }
                if (j < nbin) pfx[j] = carry + x - h;
                carry += __shfl(x, 63, 64);
            }
        }
        __syncthreads();
        for (int j = tid; j < nbin; j += 1024) cur[j] = pfx[j];
        __syncthreads();

#pragma unroll
        for (int s = 0; s < 7; ++s) {
            if (sb[s] >= 0) {
                const int p = atomicAdd(&cur[sb[s]], 1);
                sbuf[p] = svv[s];
                binbuf[p] = (unsigned short)sb[s];
            }
        }
        __syncthreads();

        for (int li = tid; li < TS; li += 1024) {
            const int bin = binbuf[li];
            part[gdst[bin] + (li - pfx[bin])] = sbuf[li];
        }
        __syncthreads();
        for (int j = tid; j < nbin; j += 1024) gdst[j] += cur[j] - pfx[j];
    }
}

// ---------------------------------------------------------------------------
// Fused sort+gather, edge side: one block per 64-edge bucket.
// ---------------------------------------------------------------------------
__global__ __launch_bounds__(1024) void k_sortgatherE(const unsigned* __restrict__ part,
                                                      const int* __restrict__ mat,
                                                      const unsigned short* __restrict__ Xpb,
                                                      const float* __restrict__ degE,
                                                      const float* __restrict__ Wdiag,
                                                      unsigned short* __restrict__ Xeb) {
    __shared__ unsigned sbuf[ECAP_E];       // 24 KB
    __shared__ int hist[64], cur[64], pfx[65];
    const int b = blockIdx.x, tid = threadIdx.x;
    const int base = mat[b * NB];
    const int end  = (b == NBE - 1) ? NNZ : mat[(b + 1) * NB];
    const int nb = end - base;

    if (tid < 64) hist[tid] = 0;
    __syncthreads();
    for (int i = tid; i < nb; i += 1024)
        atomicAdd(&hist[(part[base + i] >> 17) & 63], 1);
    __syncthreads();
    if (tid == 0) {
        int s = 0;
        for (int k = 0; k < 64; ++k) { pfx[k] = s; cur[k] = s; s += hist[k]; }
        pfx[64] = s;
    }
    __syncthreads();
    for (int i = tid; i < nb; i += 1024) {
        const unsigned u = part[base + i];
        const int p = atomicAdd(&cur[(u >> 17) & 63], 1);
        sbuf[p] = u & 0x1FFFFu;
    }
    __syncthreads();

    const int wv = tid >> 6, lane = tid & 63;
    const int q = lane >> 3, sl = lane & 7;
#pragma unroll
    for (int j = 0; j < 4; ++j) {
        const int le = wv * 4 + j;
        const int e_id = (b << 6) + le;
        const int s0 = pfx[le];
        const int n  = pfx[le + 1] - s0;
        float a0 = 0.f, a1 = 0.f, a2 = 0.f, a3 = 0.f,
              a4 = 0.f, a5 = 0.f, a6 = 0.f, a7 = 0.f;
        const int nf = n >> 3;
        int t = 0;
        for (; t + 4 <= nf; t += 4) {
            int idx[4]; uint4 u4[4];
#pragma unroll
            for (int z = 0; z < 4; ++z) idx[z] = (int)sbuf[s0 + 8 * (t + z) + q];
#pragma unroll
            for (int z = 0; z < 4; ++z)
                u4[z] = *(const uint4*)&Xpb[(size_t)idx[z] * KOUT + 8 * sl];
#pragma unroll
            for (int z = 0; z < 4; ++z) {
                a0 += bf2f_lo(u4[z].x); a1 += bf2f_hi(u4[z].x);
                a2 += bf2f_lo(u4[z].y); a3 += bf2f_hi(u4[z].y);
                a4 += bf2f_lo(u4[z].z); a5 += bf2f_hi(u4[z].z);
                a6 += bf2f_lo(u4[z].w); a7 += bf2f_hi(u4[z].w);
            }
        }
        for (; t < nf; ++t) {
            const int idx = (int)sbuf[s0 + 8 * t + q];
            const uint4 u = *(const uint4*)&Xpb[(size_t)idx * KOUT + 8 * sl];
            a0 += bf2f_lo(u.x); a1 += bf2f_hi(u.x);
            a2 += bf2f_lo(u.y); a3 += bf2f_hi(u.y);
            a4 += bf2f_lo(u.z); a5 += bf2f_hi(u.z);
            a6 += bf2f_lo(u.w); a7 += bf2f_hi(u.w);
        }
        if (n & 7) {
            const int src = nf * 8 + q;
            if (src < n) {
                const int idx = (int)sbuf[s0 + src];
                const uint4 u = *(const uint4*)&Xpb[(size_t)idx * KOUT + 8 * sl];
                a0 += bf2f_lo(u.x); a1 += bf2f_hi(u.x);
                a2 += bf2f_lo(u.y); a3 += bf2f_hi(u.y);
                a4 += bf2f_lo(u.z); a5 += bf2f_hi(u.z);
                a6 += bf2f_lo(u.w); a7 += bf2f_hi(u.w);
            }
        }
#pragma unroll
        for (int d = 8; d < 64; d <<= 1) {
            a0 += __shfl_xor(a0, d, 64); a1 += __shfl_xor(a1, d, 64);
            a2 += __shfl_xor(a2, d, 64); a3 += __shfl_xor(a3, d, 64);
            a4 += __shfl_xor(a4, d, 64); a5 += __shfl_xor(a5, d, 64);
            a6 += __shfl_xor(a6, d, 64); a7 += __shfl_xor(a7, d, 64);
        }
        if (q == 0 && e_id < NE) {
            const float s = degE[e_id] * Wdiag[e_id];
            uint4 pk;
            pk.x = (unsigned)f2bf(a0 * s) | ((unsigned)f2bf(a1 * s) << 16);
            pk.y = (unsigned)f2bf(a2 * s) | ((unsigned)f2bf(a3 * s) << 16);
            pk.z = (unsigned)f2bf(a4 * s) | ((unsigned)f2bf(a5 * s) << 16);
            pk.w = (unsigned)f2bf(a6 * s) | ((unsigned)f2bf(a7 * s) << 16);
            *(uint4*)&Xeb[(size_t)e_id * KOUT + 8 * sl] = pk;
        }
    }
}

// ---------------------------------------------------------------------------
// Fused sort+gather, vertex side: one block per 64-vertex bucket; f32 out.
// ---------------------------------------------------------------------------
__global__ __launch_bounds__(1024) void k_sortgatherV(const unsigned* __restrict__ part,
                                                      const int* __restrict__ mat,
                                                      const unsigned short* __restrict__ Xeb,
                                                      const float* __restrict__ degV,
                                                      float* __restrict__ out) {
    __shared__ unsigned sbuf[ECAP_V];       // 16 KB
    __shared__ int hist[64], cur[64], pfx[65];
    const int b = blockIdx.x, tid = threadIdx.x;
    const int base = mat[NBE * NB + b * NB] - NNZ;
    const int end  = (b == NBV - 1) ? NNZ : (mat[NBE * NB + (b + 1) * NB] - NNZ);
    const int nb = end - base;

    if (tid < 64) hist[tid] = 0;
    __syncthreads();
    for (int i = tid; i < nb; i += 1024)
        atomicAdd(&hist[(part[base + i] >> 17) & 63], 1);
    __syncthreads();
    if (tid == 0) {
        int s = 0;
        for (int k = 0; k < 64; ++k) { pfx[k] = s; cur[k] = s; s += hist[k]; }
        pfx[64] = s;
    }
    __syncthreads();
    for (int i = tid; i < nb; i += 1024) {
        const unsigned u = part[base + i];
        const int p = atomicAdd(&cur[(u >> 17) & 63], 1);
        sbuf[p] = u & 0x1FFFFu;
    }
    __syncthreads();

    const int wv = tid >> 6, lane = tid & 63;
    const int q = lane >> 3, sl = lane & 7;
#pragma unroll
    for (int j = 0; j < 4; ++j) {
        const int lv = wv * 4 + j;
        const int v_id = (b << 6) + lv;
        const int s0 = pfx[lv];
        const int n  = pfx[lv + 1] - s0;
        float a0 = 0.f, a1 = 0.f, a2 = 0.f, a3 = 0.f,
              a4 = 0.f, a5 = 0.f, a6 = 0.f, a7 = 0.f;
        const int nf = n >> 3;
        int t = 0;
        for (; t + 4 <= nf; t += 4) {
            int idx[4]; uint4 u4[4];
#pragma unroll
            for (int z = 0; z < 4; ++z) idx[z] = (int)sbuf[s0 + 8 * (t + z) + q];
#pragma unroll
            for (int z = 0; z < 4; ++z)
                u4[z] = *(const uint4*)&Xeb[(size_t)idx[z] * KOUT + 8 * sl];
#pragma unroll
            for (int z = 0; z < 4; ++z) {
                a0 += bf2f_lo(u4[z].x); a1 += bf2f_hi(u4[z].x);
                a2 += bf2f_lo(u4[z].y); a3 += bf2f_hi(u4[z].y);
                a4 += bf2f_lo(u4[z].z); a5 += bf2f_hi(u4[z].z);
                a6 += bf2f_lo(u4[z].w); a7 += bf2f_hi(u4[z].w);
            }
        }
        for (; t < nf; ++t) {
            const int idx = (int)sbuf[s0 + 8 * t + q];
            const uint4 u = *(const uint4*)&Xeb[(size_t)idx * KOUT + 8 * sl];
            a0 += bf2f_lo(u.x); a1 += bf2f_hi(u.x);
            a2 += bf2f_lo(u.y); a3 += bf2f_hi(u.y);
            a4 += bf2f_lo(u.z); a5 += bf2f_hi(u.z);
            a6 += bf2f_lo(u.w); a7 += bf2f_hi(u.w);
        }
        if (n & 7) {
            const int src = nf * 8 + q;
            if (src < n) {
                const int idx = (int)sbuf[s0 + src];
                const uint4 u = *(const uint4*)&Xeb[(size_t)idx * KOUT + 8 * sl];
                a0 += bf2f_lo(u.x); a1 += bf2f_hi(u.x);
                a2 += bf2f_lo(u.y); a3 += bf2f_hi(u.y);
                a4 += bf2f_lo(u.z); a5 += bf2f_hi(u.z);
                a6 += bf2f_lo(u.w); a7 += bf2f_hi(u.w);
            }
        }
#pragma unroll
        for (int d = 8; d < 64; d <<= 1) {
            a0 += __shfl_xor(a0, d, 64); a1 += __shfl_xor(a1, d, 64);
            a2 += __shfl_xor(a2, d, 64); a3 += __shfl_xor(a3, d, 64);
            a4 += __shfl_xor(a4, d, 64); a5 += __shfl_xor(a5, d, 64);
            a6 += __shfl_xor(a6, d, 64); a7 += __shfl_xor(a7, d, 64);
        }
        if (q == 0 && v_id < NV) {
            const float s = degV[v_id];
            *(float4*)&out[(size_t)v_id * KOUT + 8 * sl] =
                make_float4(a0 * s, a1 * s, a2 * s, a3 * s);
            *(float4*)&out[(size_t)v_id * KOUT + 8 * sl + 4] =
                make_float4(a4 * s, a5 * s, a6 * s, a7 * s);
        }
    }
}

extern "C" void kernel_launch(void* const* d_in, const int* in_sizes, int n_in,
                              void* d_out, int out_size, void* d_ws, size_t ws_size,
                              hipStream_t stream) {
    const float* X     = (const float*)d_in[0];
    const float* W     = (const float*)d_in[1];
    const float* degE  = (const float*)d_in[2];
    const float* degV  = (const float*)d_in[3];
    const float* Wdiag = (const float*)d_in[4];
    const int*   v_idx = (const int*)d_in[5];
    const int*   e_idx = (const int*)d_in[6];
    float* out = (float*)d_out;

    // Workspace (~48 MB)
    unsigned short* Xpb  = (unsigned short*)d_ws;             // NV*KOUT bf16
    unsigned short* Xeb  = Xpb + (size_t)NV * KOUT;           // NE*KOUT bf16
    unsigned*       partE = (unsigned*)(Xeb + (size_t)NE * KOUT); // NNZ u32
    unsigned*       partV = partE + NNZ;                      // NNZ u32
    int*            mat   = (int*)(partV + NNZ);              // LSCAN
    int*            bsum  = mat + LSCAN;                      // NBLK_SCAN
    unsigned short* Wb    = (unsigned short*)(bsum + ((NBLK_SCAN + 3) & ~3)); // 32 KB

    k_wb<<<(KIN * KOUT) / 256, 256, 0, stream>>>(W, Wb);

    // Project (blocks 0..195) CONCURRENT with histogram (blocks 196..451)
    k_projhist<<<PROJ_BLKS + NB, 1024, 0, stream>>>(X, Wb, Xpb, v_idx, e_idx, mat);

    k_scan1<<<NBLK_SCAN, 1024, 0, stream>>>(mat, bsum);
    k_scan23<<<NBLK_SCAN, 1024, 0, stream>>>(mat, bsum);

    // E and V coalesced partitions in ONE kernel (overlapped)
    k_partsort2<<<2 * NB, 1024, 0, stream>>>(v_idx, e_idx, mat, partE, partV);

    // Fused per-bucket sort + gather (eighth-wave: 8 entries/load round)
    k_sortgatherE<<<NBE, 1024, 0, stream>>>(partE, mat, Xpb, degE, Wdiag, Xeb);
    k_sortgatherV<<<NBV, 1024, 0, stream>>>(partV, mat, Xeb, degV, out);
}